// Round 1
// baseline (21.283 us; speedup 1.0000x reference)
//
#include <hip/hip_runtime.h>

#define KSZ 1024   // codebook size
#define NQ  8      // num quantizers

// ---------------------------------------------------------------------------
// Kernel 1: bitonic-sort each 1024-entry codebook (values only) into d_ws.
// One block (512 threads) per codebook; sort happens entirely in LDS.
// ---------------------------------------------------------------------------
__global__ __launch_bounds__(512) void sort_cb_kernel(
    const float* __restrict__ cb, float* __restrict__ sorted_out)
{
    __shared__ float s[KSZ];
    const int q = blockIdx.x;
    const float* src = cb + q * KSZ;
    for (int i = threadIdx.x; i < KSZ; i += 512) s[i] = src[i];
    __syncthreads();

    for (int k = 2; k <= KSZ; k <<= 1) {
        for (int j = k >> 1; j > 0; j >>= 1) {
            const int t = threadIdx.x;                       // 0..511, one comparator each
            const int i = ((t & ~(j - 1)) << 1) | (t & (j - 1));
            const int p = i + j;
            const float a = s[i];
            const float b = s[p];
            const bool asc = ((i & k) == 0);
            const bool do_swap = asc ? (a > b) : (a < b);
            if (do_swap) { s[i] = b; s[p] = a; }
            __syncthreads();
        }
    }
    for (int i = threadIdx.x; i < KSZ; i += 512)
        sorted_out[q * KSZ + i] = s[i];
}

// ---------------------------------------------------------------------------
// Kernel 2: fused encoder -> residual VQ (binary search in sorted LDS
// codebooks) -> decoder. One thread per (b, n) element.
// ---------------------------------------------------------------------------
__global__ __launch_bounds__(256) void rvq_kernel(
    const float* __restrict__ x,
    const float* __restrict__ ew0, const float* __restrict__ eb0,
    const float* __restrict__ ew1, const float* __restrict__ eb1,
    const float* __restrict__ dw0, const float* __restrict__ db0,
    const float* __restrict__ dw1, const float* __restrict__ db1,
    const float* __restrict__ scb_g,
    float* __restrict__ out, int total)
{
    __shared__ __attribute__((aligned(16))) float scb[NQ][KSZ];
    {   // cooperative 32 KB load of all sorted codebooks (hot in L2)
        const float4* src = (const float4*)scb_g;
        float4* dst = (float4*)&scb[0][0];
        for (int i = threadIdx.x; i < (NQ * KSZ / 4); i += 256) dst[i] = src[i];
    }
    __syncthreads();

    const int idx = blockIdx.x * 256 + threadIdx.x;
    if (idx >= total) return;

    // ---- encoder: Linear(4,2) + ReLU -> Linear(2,1) ----
    const float4 xi = reinterpret_cast<const float4*>(x)[idx];
    const float h0 = fmaxf(0.0f,
        xi.x * ew0[0] + xi.y * ew0[1] + xi.z * ew0[2] + xi.w * ew0[3] + eb0[0]);
    const float h1 = fmaxf(0.0f,
        xi.x * ew0[4] + xi.y * ew0[5] + xi.z * ew0[6] + xi.w * ew0[7] + eb0[1]);
    const float z = h0 * ew1[0] + h1 * ew1[1] + eb1[0];

    // ---- residual VQ: 8 sequential levels, 1-D nearest via binary search ----
    float r = z;
    float qsum = 0.0f;
    #pragma unroll
    for (int lvl = 0; lvl < NQ; ++lvl) {
        const float* c = scb[lvl];
        // branchless lower-bound: base = (#elements < r), capped at KSZ-1
        int base = 0;
        #pragma unroll
        for (int step = KSZ / 2; step > 0; step >>= 1)
            base += (c[base + step - 1] < r) ? step : 0;
        const int i0 = (base > 0)       ? base - 1 : 0;
        const int i2 = (base < KSZ - 1) ? base + 1 : KSZ - 1;
        const float c0 = c[i0];
        const float c1 = c[base];
        const float c2 = c[i2];
        // reference's expanded distance: (r^2 - 2*(r*c)) + c^2
        const float rr = r * r;
        const float d0 = (rr - 2.0f * (r * c0)) + c0 * c0;
        const float d1 = (rr - 2.0f * (r * c1)) + c1 * c1;
        const float d2 = (rr - 2.0f * (r * c2)) + c2 * c2;
        float bd = d0, bc = c0;
        if (d1 < bd) { bd = d1; bc = c1; }
        if (d2 < bd) { bd = d2; bc = c2; }
        qsum += bc;   // qout accumulates quant
        r    -= bc;   // residual update
    }

    // ---- decoder: Linear(1,2) + ReLU -> Linear(2,4) ----
    const float g0 = fmaxf(0.0f, qsum * dw0[0] + db0[0]);
    const float g1 = fmaxf(0.0f, qsum * dw0[1] + db0[1]);
    float4 o;
    o.x = g0 * dw1[0] + g1 * dw1[1] + db1[0];
    o.y = g0 * dw1[2] + g1 * dw1[3] + db1[1];
    o.z = g0 * dw1[4] + g1 * dw1[5] + db1[2];
    o.w = g0 * dw1[6] + g1 * dw1[7] + db1[3];
    reinterpret_cast<float4*>(out)[idx] = o;
}

extern "C" void kernel_launch(void* const* d_in, const int* in_sizes, int n_in,
                              void* d_out, int out_size, void* d_ws, size_t ws_size,
                              hipStream_t stream)
{
    const float* x   = (const float*)d_in[0];
    const float* ew0 = (const float*)d_in[1];
    const float* eb0 = (const float*)d_in[2];
    const float* ew1 = (const float*)d_in[3];
    const float* eb1 = (const float*)d_in[4];
    const float* dw0 = (const float*)d_in[5];
    const float* db0 = (const float*)d_in[6];
    const float* dw1 = (const float*)d_in[7];
    const float* db1 = (const float*)d_in[8];
    const float* cb  = (const float*)d_in[9];

    float* sorted = (float*)d_ws;            // 8 * 1024 * 4 B = 32 KB scratch
    float* outp   = (float*)d_out;

    sort_cb_kernel<<<NQ, 512, 0, stream>>>(cb, sorted);

    const int total = in_sizes[0] / 4;       // B*N = 131072 elements
    rvq_kernel<<<(total + 255) / 256, 256, 0, stream>>>(
        x, ew0, eb0, ew1, eb1, dw0, db0, dw1, db1, sorted, outp, total);
}